// Round 4
// baseline (1289.765 us; speedup 1.0000x reference)
//
#include <hip/hip_runtime.h>

// ResRGCN: h=x@W1+b1; 2x {per-(dst,rel) mean aggr -> [h|agg]@[root;W_r]+bias, h+=relu}; out=h@W2+b2
// Layer 3 of the reference is dead (output discarded) and is skipped.
// Edges counting-sorted by key = dst*8+type; a block's NPB=16 nodes own a
// contiguous edge range. k_conv processes edges wave-parallel: per edge one
// uniform sorted-word load + one 128B feature-row gather + one ds_add_f32 into
// a per-(node,rel,ch) f32 LDS accumulator (fire-and-forget, no serial chains).
// MFMA A-fragments read the accumulator, scale by 1/cnt, convert to bf16 inline.

#define HDIM 64
#define RREL 8
#define KCAT 576   // 64 (root/self) + 8*64 (relations)
#define NPB  16    // nodes per workgroup
#define ACCW 516   // padded acc row (f32): 516 mod 32 == 4 -> conflict-light

typedef short  short8 __attribute__((ext_vector_type(8)));
typedef __bf16 bf16x8 __attribute__((ext_vector_type(8)));
typedef float  f32x4  __attribute__((ext_vector_type(4)));
typedef unsigned int uint;
typedef unsigned short ushort;

static __device__ __forceinline__ ushort f2bf(float f) {
  uint u = __builtin_bit_cast(uint, f);
  u += 0x7FFFu + ((u >> 16) & 1u);
  return (ushort)(u >> 16);
}
static __device__ __forceinline__ float bf2f(ushort s) {
  uint u = ((uint)s) << 16;
  return __builtin_bit_cast(float, u);
}

// ---- weight prep: wt_lin1[j][k]=lin1_w[k][j]; wt_conv[l][j][k] = cat(root_l, W_r)^T in bf16
__global__ void k_prep_wt(const float* __restrict__ lin1_w, const float* __restrict__ bases,
                          const float* __restrict__ comp, const float* __restrict__ root,
                          ushort* __restrict__ wt_lin1, ushort* __restrict__ wt_conv) {
  int t = blockIdx.x * 256 + threadIdx.x;
  if (t < HDIM * HDIM) {
    int j = t >> 6, k = t & 63;
    wt_lin1[t] = f2bf(lin1_w[k * HDIM + j]);
  }
  if (t < 2 * HDIM * KCAT) {
    int l = t / (HDIM * KCAT);
    int rem = t - l * (HDIM * KCAT);
    int j = rem / KCAT;
    int k = rem - j * KCAT;
    float v;
    if (k < HDIM) {
      v = root[(l * HDIM + k) * HDIM + j];
    } else {
      int r = (k - HDIM) >> 6;
      int i = (k - HDIM) & 63;
      v = 0.f;
      #pragma unroll
      for (int b = 0; b < 4; ++b)
        v += comp[(l * RREL + r) * 4 + b] * bases[((l * 4 + b) * HDIM + i) * HDIM + j];
    }
    wt_conv[t] = f2bf(v);
  }
}

// ---- build CSR over keys = dst*8 + type (M = 8N bins)
__global__ void k_hist(const int* __restrict__ dst, const int* __restrict__ et, int E,
                       uint* __restrict__ deg) {
  int e = blockIdx.x * 256 + threadIdx.x;
  if (e < E) atomicAdd(&deg[dst[e] * RREL + et[e]], 1u);
}

__global__ void k_scan1(const uint* __restrict__ deg, uint* __restrict__ off,
                        uint* __restrict__ bsum, int M) {
  __shared__ uint s[256];
  int t = threadIdx.x;
  int base = blockIdx.x * 1024 + t * 4;
  uint v0 = 0, v1 = 0, v2 = 0, v3 = 0;
  if (base + 3 < M) {
    uint4 u = *(const uint4*)(deg + base);
    v0 = u.x; v1 = u.y; v2 = u.z; v3 = u.w;
  } else {
    if (base < M)     v0 = deg[base];
    if (base + 1 < M) v1 = deg[base + 1];
    if (base + 2 < M) v2 = deg[base + 2];
    if (base + 3 < M) v3 = deg[base + 3];
  }
  uint tsum = v0 + v1 + v2 + v3;
  s[t] = tsum;
  __syncthreads();
  for (int o = 1; o < 256; o <<= 1) {
    uint u = (t >= o) ? s[t - o] : 0u;
    __syncthreads();
    s[t] += u;
    __syncthreads();
  }
  uint ex = s[t] - tsum;
  if (base < M)     off[base]     = ex;
  if (base + 1 < M) off[base + 1] = ex + v0;
  if (base + 2 < M) off[base + 2] = ex + v0 + v1;
  if (base + 3 < M) off[base + 3] = ex + v0 + v1 + v2;
  if (t == 255) bsum[blockIdx.x] = s[255];
}

__global__ void k_scan2(uint* __restrict__ bsum, uint* __restrict__ off, int nblk, int M, uint E) {
  __shared__ uint s[1024];
  int t = threadIdx.x;
  uint v = (t < nblk) ? bsum[t] : 0u;
  s[t] = v;
  __syncthreads();
  for (int o = 1; o < 1024; o <<= 1) {
    uint u = (t >= o) ? s[t - o] : 0u;
    __syncthreads();
    s[t] += u;
    __syncthreads();
  }
  if (t < nblk) bsum[t] = s[t] - v;
  if (t == 0) off[M] = E;
}

__global__ void k_scan3(uint* __restrict__ off, const uint* __restrict__ bsum, int M) {
  int i = blockIdx.x * 256 + threadIdx.x;
  if (i < M) off[i] += bsum[i >> 10];
}

// counting-sort scatter; atomicSub on deg leaves it zeroed (self-restoring).
// payload: src (17b) | rel (3b @17) | dst&15 (4b @20)
__global__ void k_scatter(const int* __restrict__ src, const int* __restrict__ dst,
                          const int* __restrict__ et, int E, const uint* __restrict__ off,
                          uint* __restrict__ deg, uint* __restrict__ sorted) {
  int e = blockIdx.x * 256 + threadIdx.x;
  if (e < E) {
    int d = dst[e];
    int r = et[e];
    int key = d * RREL + r;
    uint p = off[key] + atomicSub(&deg[key], 1u) - 1u;
    sorted[p] = (uint)src[e] | ((uint)r << 17) | ((uint)(d & 15) << 20);
  }
}

// ---- lin1: h = x @ W1 + b1 (MFMA over K=64), writes f32 + bf16 copies
__global__ void k_lin1(const float* __restrict__ x, const ushort* __restrict__ wt,
                       const float* __restrict__ bias, float* __restrict__ h,
                       ushort* __restrict__ hb, int N) {
  __shared__ ushort A[NPB][72];
  int nodebase = blockIdx.x * NPB;
  for (int i = threadIdx.x; i < NPB * HDIM; i += 256) {
    int nl = i >> 6, c = i & 63;
    int n = nodebase + nl;
    A[nl][c] = (n < N) ? f2bf(x[(size_t)n * HDIM + c]) : (ushort)0;
  }
  __syncthreads();
  int lane = threadIdx.x & 63, wid = threadIdx.x >> 6;
  int m16 = lane & 15, khi = lane >> 4;
  int colbase = wid * 16;
  f32x4 acc = {0.f, 0.f, 0.f, 0.f};
  #pragma unroll
  for (int kk = 0; kk < HDIM; kk += 32) {
    int k0 = kk + khi * 8;
    short8 av = *(const short8*)&A[m16][k0];
    short8 bv = *(const short8*)&wt[(colbase + m16) * HDIM + k0];
    acc = __builtin_amdgcn_mfma_f32_16x16x32_bf16(
        __builtin_bit_cast(bf16x8, av), __builtin_bit_cast(bf16x8, bv), acc, 0, 0, 0);
  }
  int j = colbase + m16;
  float bj = bias[j];
  #pragma unroll
  for (int r = 0; r < 4; ++r) {
    int nl = khi * 4 + r;
    int n = nodebase + nl;
    if (n < N) {
      float v = acc[r] + bj;
      h[(size_t)n * HDIM + j] = v;
      hb[(size_t)n * HDIM + j] = f2bf(v);
    }
  }
}

// ---- fused RGCN layer: wave-parallel edge aggregation into LDS f32 + MFMA
__global__ void k_conv(const uint* __restrict__ off8, const uint* __restrict__ sorted,
                       const float* __restrict__ h_in, const ushort* __restrict__ hb_in,
                       const ushort* __restrict__ wt, const float* __restrict__ bias,
                       float* __restrict__ h_out, ushort* __restrict__ hb_out, int N) {
  __shared__ float  acc[NPB][ACCW];   // 33 KB: per-(node, rel*64+ch) sums
  __shared__ ushort hself[NPB][72];   // 2.3 KB
  __shared__ float  rcpc[NPB][RREL];  // 0.5 KB
  int t = threadIdx.x;
  int lane = t & 63, wid = t >> 6;
  int nb0 = blockIdx.x * NPB;

  // zero acc (vectorized)
  {
    f32x4* a4 = (f32x4*)&acc[0][0];
    f32x4 z = {0.f, 0.f, 0.f, 0.f};
    #pragma unroll
    for (int i = 0; i < (NPB * ACCW / 4) / 256 + 1; ++i) {
      int idx = t + i * 256;
      if (idx < NPB * ACCW / 4) a4[idx] = z;
    }
  }
  // hself: thread t loads 4 consecutive ushorts (8B)
  {
    int nl = t >> 4, c = (t & 15) * 4;
    int n = nb0 + nl;
    uint2 v = {0u, 0u};
    if (n < N) v = *(const uint2*)&hb_in[(size_t)n * HDIM + c];
    *(uint2*)&hself[nl][c] = v;
  }
  // per-(node,rel) reciprocal counts from CSR offsets
  if (t < NPB * RREL) {
    int nl = t >> 3, r = t & 7;
    int n = nb0 + nl;
    float c = 0.f;
    if (n < N) {
      uint a = off8[(uint)n * RREL + r], b = off8[(uint)n * RREL + r + 1];
      c = (float)(b - a);
    }
    rcpc[nl][r] = (c > 0.f) ? __builtin_amdgcn_rcpf(c) : 0.f;
  }
  __syncthreads();

  // edge phase: block's edge range is contiguous in sorted
  {
    uint kb = (uint)nb0 * RREL;
    uint ke = (uint)((nb0 + NPB <= N) ? (nb0 + NPB) : N) * RREL;
    uint e0 = (uint)__builtin_amdgcn_readfirstlane((int)off8[kb]);
    uint e1 = (uint)__builtin_amdgcn_readfirstlane((int)off8[ke]);
    const ushort* hlane = hb_in + lane;
    for (uint e = e0 + (uint)wid * 4u; e < e1; e += 16u) {
      #pragma unroll
      for (int u = 0; u < 4; ++u) {
        uint ee = e + (uint)u;
        uint ec = (ee < e1) ? ee : (e1 - 1u);   // clamp: load valid, add 0
        uint w = sorted[ec];
        uint s  = w & 0x1FFFFu;
        uint rl = (w >> 17) & 7u;
        uint nl = (w >> 20) & 15u;
        float v = bf2f(hlane[(size_t)s << 6]);  // 128B coalesced row gather
        v = (ee < e1) ? v : 0.f;
        atomicAdd(&acc[nl][rl * HDIM + lane], v);  // ds_add_f32, no return
      }
    }
  }
  __syncthreads();

  // MFMA: [16 x 576] @ [576 x 64]; A-fragments from hself / scaled acc
  int m16 = lane & 15, khi = lane >> 4;
  int colbase = wid * 16;
  f32x4 cacc = {0.f, 0.f, 0.f, 0.f};
  #pragma unroll
  for (int kk = 0; kk < KCAT; kk += 32) {
    int k0 = kk + khi * 8;
    bf16x8 av;
    if (kk < HDIM) {
      av = __builtin_bit_cast(bf16x8, *(const short8*)&hself[m16][k0]);
    } else {
      int rel = (k0 - HDIM) >> 6;
      int off = (k0 - HDIM) & 63;
      const float* ap = &acc[m16][rel * HDIM + off];
      f32x4 p0 = *(const f32x4*)ap;
      f32x4 p1 = *(const f32x4*)(ap + 4);
      float rc = rcpc[m16][rel];
      av[0] = (__bf16)(p0[0] * rc);
      av[1] = (__bf16)(p0[1] * rc);
      av[2] = (__bf16)(p0[2] * rc);
      av[3] = (__bf16)(p0[3] * rc);
      av[4] = (__bf16)(p1[0] * rc);
      av[5] = (__bf16)(p1[1] * rc);
      av[6] = (__bf16)(p1[2] * rc);
      av[7] = (__bf16)(p1[3] * rc);
    }
    short8 bv = *(const short8*)&wt[(uint)(colbase + m16) * KCAT + k0];
    cacc = __builtin_amdgcn_mfma_f32_16x16x32_bf16(
        av, __builtin_bit_cast(bf16x8, bv), cacc, 0, 0, 0);
  }
  int j = colbase + m16;
  float bj = bias[j];
  #pragma unroll
  for (int r = 0; r < 4; ++r) {
    int nl = khi * 4 + r;
    int n = nb0 + nl;
    if (n < N) {
      float v = cacc[r] + bj;
      float hn = h_in[(uint)n * HDIM + j] + fmaxf(v, 0.f);
      h_out[(uint)n * HDIM + j] = hn;
      hb_out[(uint)n * HDIM + j] = f2bf(hn);
    }
  }
}

// ---- lin2: out = h @ W2 + b2  (OUT=2), float4 loads
__global__ void k_lin2(const float* __restrict__ h, const float* __restrict__ w,
                       const float* __restrict__ b, float* __restrict__ out, int N) {
  int n = blockIdx.x * 256 + threadIdx.x;
  if (n >= N) return;
  const f32x4* hr = (const f32x4*)(h + (size_t)n * HDIM);
  const f32x4* wr = (const f32x4*)w;
  float a0 = b[0], a1 = b[1];
  #pragma unroll
  for (int i = 0; i < HDIM / 4; ++i) {
    f32x4 hv = hr[i];
    f32x4 w0 = wr[2 * i];
    f32x4 w1 = wr[2 * i + 1];
    a0 += hv[0] * w0[0] + hv[1] * w0[2] + hv[2] * w1[0] + hv[3] * w1[2];
    a1 += hv[0] * w0[1] + hv[1] * w0[3] + hv[2] * w1[1] + hv[3] * w1[3];
  }
  out[2 * n] = a0;
  out[2 * n + 1] = a1;
}

extern "C" void kernel_launch(void* const* d_in, const int* in_sizes, int n_in,
                              void* d_out, int out_size, void* d_ws, size_t ws_size,
                              hipStream_t stream) {
  const float* x      = (const float*)d_in[0];
  const int*   ei     = (const int*)d_in[1];
  const int*   et     = (const int*)d_in[2];
  const float* lin1_w = (const float*)d_in[3];
  const float* lin1_b = (const float*)d_in[4];
  const float* bases  = (const float*)d_in[5];
  const float* comp   = (const float*)d_in[6];
  const float* root   = (const float*)d_in[7];
  const float* cbias  = (const float*)d_in[8];
  const float* lin2_w = (const float*)d_in[9];
  const float* lin2_b = (const float*)d_in[10];
  float* out = (float*)d_out;

  int N = in_sizes[0] / HDIM;
  int E = in_sizes[2];
  int M = N * RREL;
  const int* srcp = ei;
  const int* dstp = ei + E;

  char* p = (char*)d_ws;
  auto carve = [&](size_t bytes) { char* r = p; p += (bytes + 255) & ~(size_t)255; return r; };
  float*  h_a     = (float*)carve((size_t)N * HDIM * 4);
  float*  h_b     = (float*)carve((size_t)N * HDIM * 4);
  ushort* hb_a    = (ushort*)carve((size_t)N * HDIM * 2);
  ushort* hb_b    = (ushort*)carve((size_t)N * HDIM * 2);
  uint*   sorted  = (uint*)carve((size_t)E * 4);
  uint*   deg8    = (uint*)carve((size_t)M * 4);
  uint*   off8    = (uint*)carve((size_t)(M + 1) * 4);
  uint*   bsum    = (uint*)carve(4096);
  ushort* wt_lin1 = (ushort*)carve((size_t)HDIM * HDIM * 2);
  ushort* wt_conv = (ushort*)carve((size_t)2 * HDIM * KCAT * 2);

  hipMemsetAsync(deg8, 0, (size_t)M * 4, stream);

  int eb    = (E + 255) / 256;
  int nb    = (N + 255) / 256;
  int nwg   = (N + NPB - 1) / NPB;
  int nblk1 = (M + 1023) / 1024;   // <= 1024 (N <= 131072)
  int mb    = (M + 255) / 256;

  k_prep_wt<<<(2 * HDIM * KCAT + 255) / 256, 256, 0, stream>>>(lin1_w, bases, comp, root, wt_lin1, wt_conv);
  k_hist<<<eb, 256, 0, stream>>>(dstp, et, E, deg8);
  k_scan1<<<nblk1, 256, 0, stream>>>(deg8, off8, bsum, M);
  k_scan2<<<1, 1024, 0, stream>>>(bsum, off8, nblk1, M, (uint)E);
  k_scan3<<<mb, 256, 0, stream>>>(off8, bsum, M);
  k_scatter<<<eb, 256, 0, stream>>>(srcp, dstp, et, E, off8, deg8, sorted);

  k_lin1<<<nwg, 256, 0, stream>>>(x, wt_lin1, lin1_b, h_a, hb_a, N);
  k_conv<<<nwg, 256, 0, stream>>>(off8, sorted, h_a, hb_a, wt_conv, cbias, h_b, hb_b, N);
  k_conv<<<nwg, 256, 0, stream>>>(off8, sorted, h_b, hb_b, wt_conv + HDIM * KCAT, cbias + HDIM, h_a, hb_a, N);
  k_lin2<<<nb, 256, 0, stream>>>(h_a, lin2_w, lin2_b, out, N);
}

// Round 5
// 384.620 us; speedup vs baseline: 3.3533x; 3.3533x over previous
//
#include <hip/hip_runtime.h>

// ResRGCN: h=x@W1+b1; 2x {per-(dst,rel) mean aggr -> [h|agg]@[root;W_r]+bias, h+=relu}; out=h@W2+b2
// Layer 3 of the reference is dead (output discarded) and is skipped.
// Edges counting-sorted by key = dst*8+type -> per-(node,rel) segments contiguous.
// k_conv per node: chunk-of-16 edge walk -- scalar s_load_dwordx4 index reads +
// 16 unguarded row-gathers in flight + scalar-state boundary-flush (readlane for
// the next boundary). No exec-masked guards around loads (r3 lesson), no extra
// LDS (r4 lesson: occupancy stays at 8 blocks/CU).

#define HDIM 64
#define RREL 8
#define KCAT 576   // 64 (root/self) + 8*64 (relations)
#define NPB  16    // nodes per workgroup in MFMA kernels
#define APAD 584   // padded LDS row

typedef short  short8 __attribute__((ext_vector_type(8)));
typedef __bf16 bf16x8 __attribute__((ext_vector_type(8)));
typedef float  f32x4  __attribute__((ext_vector_type(4)));
typedef unsigned int uint;
typedef unsigned short ushort;

static __device__ __forceinline__ ushort f2bf(float f) {
  uint u = __builtin_bit_cast(uint, f);
  u += 0x7FFFu + ((u >> 16) & 1u);
  return (ushort)(u >> 16);
}
static __device__ __forceinline__ float bf2f(ushort s) {
  uint u = ((uint)s) << 16;
  return __builtin_bit_cast(float, u);
}

// ---- weight prep: wt_lin1[j][k]=lin1_w[k][j]; wt_conv[l][j][k] = cat(root_l, W_r)^T in bf16
__global__ void k_prep_wt(const float* __restrict__ lin1_w, const float* __restrict__ bases,
                          const float* __restrict__ comp, const float* __restrict__ root,
                          ushort* __restrict__ wt_lin1, ushort* __restrict__ wt_conv) {
  int t = blockIdx.x * 256 + threadIdx.x;
  if (t < HDIM * HDIM) {
    int j = t >> 6, k = t & 63;
    wt_lin1[t] = f2bf(lin1_w[k * HDIM + j]);
  }
  if (t < 2 * HDIM * KCAT) {
    int l = t / (HDIM * KCAT);
    int rem = t - l * (HDIM * KCAT);
    int j = rem / KCAT;
    int k = rem - j * KCAT;
    float v;
    if (k < HDIM) {
      v = root[(l * HDIM + k) * HDIM + j];
    } else {
      int r = (k - HDIM) >> 6;
      int i = (k - HDIM) & 63;
      v = 0.f;
      #pragma unroll
      for (int b = 0; b < 4; ++b)
        v += comp[(l * RREL + r) * 4 + b] * bases[((l * 4 + b) * HDIM + i) * HDIM + j];
    }
    wt_conv[t] = f2bf(v);
  }
}

// ---- build CSR over keys = dst*8 + type (M = 8N bins)
__global__ void k_hist(const int* __restrict__ dst, const int* __restrict__ et, int E,
                       uint* __restrict__ deg) {
  int e = blockIdx.x * 256 + threadIdx.x;
  if (e < E) atomicAdd(&deg[dst[e] * RREL + et[e]], 1u);
}

__global__ void k_scan1(const uint* __restrict__ deg, uint* __restrict__ off,
                        uint* __restrict__ bsum, int M) {
  __shared__ uint s[256];
  int t = threadIdx.x;
  int base = blockIdx.x * 1024 + t * 4;
  uint v0 = 0, v1 = 0, v2 = 0, v3 = 0;
  if (base + 3 < M) {
    uint4 u = *(const uint4*)(deg + base);
    v0 = u.x; v1 = u.y; v2 = u.z; v3 = u.w;
  } else {
    if (base < M)     v0 = deg[base];
    if (base + 1 < M) v1 = deg[base + 1];
    if (base + 2 < M) v2 = deg[base + 2];
    if (base + 3 < M) v3 = deg[base + 3];
  }
  uint tsum = v0 + v1 + v2 + v3;
  s[t] = tsum;
  __syncthreads();
  for (int o = 1; o < 256; o <<= 1) {
    uint u = (t >= o) ? s[t - o] : 0u;
    __syncthreads();
    s[t] += u;
    __syncthreads();
  }
  uint ex = s[t] - tsum;
  if (base < M)     off[base]     = ex;
  if (base + 1 < M) off[base + 1] = ex + v0;
  if (base + 2 < M) off[base + 2] = ex + v0 + v1;
  if (base + 3 < M) off[base + 3] = ex + v0 + v1 + v2;
  if (t == 255) bsum[blockIdx.x] = s[255];
}

__global__ void k_scan2(uint* __restrict__ bsum, uint* __restrict__ off, int nblk, int M, uint E) {
  __shared__ uint s[1024];
  int t = threadIdx.x;
  uint v = (t < nblk) ? bsum[t] : 0u;
  s[t] = v;
  __syncthreads();
  for (int o = 1; o < 1024; o <<= 1) {
    uint u = (t >= o) ? s[t - o] : 0u;
    __syncthreads();
    s[t] += u;
    __syncthreads();
  }
  if (t < nblk) bsum[t] = s[t] - v;
  if (t == 0) off[M] = E;
}

__global__ void k_scan3(uint* __restrict__ off, const uint* __restrict__ bsum, int M) {
  int i = blockIdx.x * 256 + threadIdx.x;
  if (i < M) off[i] += bsum[i >> 10];
}

// counting-sort scatter; atomicSub on deg leaves it zeroed (self-restoring)
__global__ void k_scatter(const int* __restrict__ src, const int* __restrict__ dst,
                          const int* __restrict__ et, int E, const uint* __restrict__ off,
                          uint* __restrict__ deg, uint* __restrict__ sorted) {
  int e = blockIdx.x * 256 + threadIdx.x;
  if (e < E) {
    int key = dst[e] * RREL + et[e];
    uint p = off[key] + atomicSub(&deg[key], 1u) - 1u;
    sorted[p] = (uint)src[e];
  }
}

// ---- lin1: h = x @ W1 + b1 (MFMA over K=64), writes f32 + bf16 copies
__global__ void k_lin1(const float* __restrict__ x, const ushort* __restrict__ wt,
                       const float* __restrict__ bias, float* __restrict__ h,
                       ushort* __restrict__ hb, int N) {
  __shared__ ushort A[NPB][72];
  int nodebase = blockIdx.x * NPB;
  for (int i = threadIdx.x; i < NPB * HDIM; i += 256) {
    int nl = i >> 6, c = i & 63;
    int n = nodebase + nl;
    A[nl][c] = (n < N) ? f2bf(x[(size_t)n * HDIM + c]) : (ushort)0;
  }
  __syncthreads();
  int lane = threadIdx.x & 63, wid = threadIdx.x >> 6;
  int m16 = lane & 15, khi = lane >> 4;
  int colbase = wid * 16;
  f32x4 acc = {0.f, 0.f, 0.f, 0.f};
  #pragma unroll
  for (int kk = 0; kk < HDIM; kk += 32) {
    int k0 = kk + khi * 8;
    short8 av = *(const short8*)&A[m16][k0];
    short8 bv = *(const short8*)&wt[(colbase + m16) * HDIM + k0];
    acc = __builtin_amdgcn_mfma_f32_16x16x32_bf16(
        __builtin_bit_cast(bf16x8, av), __builtin_bit_cast(bf16x8, bv), acc, 0, 0, 0);
  }
  int j = colbase + m16;
  float bj = bias[j];
  #pragma unroll
  for (int r = 0; r < 4; ++r) {
    int nl = khi * 4 + r;
    int n = nodebase + nl;
    if (n < N) {
      float v = acc[r] + bj;
      h[(size_t)n * HDIM + j] = v;
      hb[(size_t)n * HDIM + j] = f2bf(v);
    }
  }
}

// ---- fused RGCN layer: chunk-16 gather pipeline + scalar boundary-flush walk
__global__ void k_conv(const uint* __restrict__ off8, const uint* __restrict__ sorted,
                       const float* __restrict__ h_in, const ushort* __restrict__ hb_in,
                       const ushort* __restrict__ wt, const float* __restrict__ bias,
                       float* __restrict__ h_out, ushort* __restrict__ hb_out, int N) {
  __shared__ ushort A[NPB][APAD];
  int nodebase = blockIdx.x * NPB;
  int lane = threadIdx.x & 63, wid = threadIdx.x >> 6;
  const ushort* hlane = hb_in + lane;

  for (int q = 0; q < 4; ++q) {
    int nl = wid * 4 + q;
    int n = nodebase + nl;
    if (n < N) {
      A[nl][lane] = hb_in[(uint)n * HDIM + lane];
      // boundaries: lanes 0..8 hold off8[n*8 .. n*8+8]
      uint bv = (lane < 9) ? off8[(uint)n * RREL + lane] : 0u;
      uint s0 = (uint)__builtin_amdgcn_readlane((int)bv, 0);
      uint s1 = (uint)__builtin_amdgcn_readlane((int)bv, 8);
      float run = 0.f;
      int rel = 0;
      uint prevb = s0;
      uint nextb = (uint)__builtin_amdgcn_readlane((int)bv, 1);
      for (uint base = s0; base < s1; base += 16u) {
        // 16 index words via scalar loads (may overrun segment; reads stay in ws)
        const uint* sp = sorted + base;
        uint4 w0 = *(const uint4*)(sp);
        uint4 w1 = *(const uint4*)(sp + 4);
        uint4 w2 = *(const uint4*)(sp + 8);
        uint4 w3 = *(const uint4*)(sp + 12);
        uint idx[16] = {w0.x, w0.y, w0.z, w0.w, w1.x, w1.y, w1.z, w1.w,
                        w2.x, w2.y, w2.z, w2.w, w3.x, w3.y, w3.z, w3.w};
        float g[16];
        #pragma unroll
        for (int j = 0; j < 16; ++j)
          g[j] = bf2f(hlane[(size_t)(idx[j] & 0x1FFFFu) << 6]);  // 16 gathers in flight
        uint m = s1 - base;                                       // scalar
        #pragma unroll
        for (int j = 0; j < 16; ++j) {
          if ((uint)j < m) {                                      // scalar branch
            uint pos = base + (uint)j;
            while (pos >= nextb) {                                // scalar flush walk
              float mean = run * __builtin_amdgcn_rcpf(fmaxf((float)(nextb - prevb), 1.0f));
              A[nl][HDIM + rel * HDIM + lane] = f2bf(mean);
              run = 0.f;
              ++rel;
              prevb = nextb;
              nextb = (uint)__builtin_amdgcn_readlane((int)bv, rel + 1);
            }
            run += g[j];
          }
        }
      }
      while (rel < RREL) {                                        // trailing flushes
        float mean = run * __builtin_amdgcn_rcpf(fmaxf((float)(nextb - prevb), 1.0f));
        A[nl][HDIM + rel * HDIM + lane] = f2bf(mean);
        run = 0.f;
        ++rel;
        prevb = nextb;
        if (rel < RREL)
          nextb = (uint)__builtin_amdgcn_readlane((int)bv, rel + 1);
      }
    } else {
      A[nl][lane] = 0;
      #pragma unroll
      for (int r = 0; r < RREL; ++r) A[nl][HDIM + r * HDIM + lane] = 0;
    }
  }
  __syncthreads();

  int m16 = lane & 15, khi = lane >> 4;
  int colbase = wid * 16;
  f32x4 acc = {0.f, 0.f, 0.f, 0.f};
  #pragma unroll
  for (int kk = 0; kk < KCAT; kk += 32) {
    int k0 = kk + khi * 8;
    short8 av = *(const short8*)&A[m16][k0];
    short8 bv = *(const short8*)&wt[(uint)(colbase + m16) * KCAT + k0];
    acc = __builtin_amdgcn_mfma_f32_16x16x32_bf16(
        __builtin_bit_cast(bf16x8, av), __builtin_bit_cast(bf16x8, bv), acc, 0, 0, 0);
  }
  int j = colbase + m16;
  float bj = bias[j];
  #pragma unroll
  for (int r = 0; r < 4; ++r) {
    int nl = khi * 4 + r;
    int n = nodebase + nl;
    if (n < N) {
      float v = acc[r] + bj;
      float hn = h_in[(uint)n * HDIM + j] + fmaxf(v, 0.f);
      h_out[(uint)n * HDIM + j] = hn;
      hb_out[(uint)n * HDIM + j] = f2bf(hn);
    }
  }
}

// ---- lin2: out = h @ W2 + b2  (OUT=2), float4 loads
__global__ void k_lin2(const float* __restrict__ h, const float* __restrict__ w,
                       const float* __restrict__ b, float* __restrict__ out, int N) {
  int n = blockIdx.x * 256 + threadIdx.x;
  if (n >= N) return;
  const f32x4* hr = (const f32x4*)(h + (size_t)n * HDIM);
  const f32x4* wr = (const f32x4*)w;
  float a0 = b[0], a1 = b[1];
  #pragma unroll
  for (int i = 0; i < HDIM / 4; ++i) {
    f32x4 hv = hr[i];
    f32x4 w0 = wr[2 * i];
    f32x4 w1 = wr[2 * i + 1];
    a0 += hv[0] * w0[0] + hv[1] * w0[2] + hv[2] * w1[0] + hv[3] * w1[2];
    a1 += hv[0] * w0[1] + hv[1] * w0[3] + hv[2] * w1[1] + hv[3] * w1[3];
  }
  out[2 * n] = a0;
  out[2 * n + 1] = a1;
}

extern "C" void kernel_launch(void* const* d_in, const int* in_sizes, int n_in,
                              void* d_out, int out_size, void* d_ws, size_t ws_size,
                              hipStream_t stream) {
  const float* x      = (const float*)d_in[0];
  const int*   ei     = (const int*)d_in[1];
  const int*   et     = (const int*)d_in[2];
  const float* lin1_w = (const float*)d_in[3];
  const float* lin1_b = (const float*)d_in[4];
  const float* bases  = (const float*)d_in[5];
  const float* comp   = (const float*)d_in[6];
  const float* root   = (const float*)d_in[7];
  const float* cbias  = (const float*)d_in[8];
  const float* lin2_w = (const float*)d_in[9];
  const float* lin2_b = (const float*)d_in[10];
  float* out = (float*)d_out;

  int N = in_sizes[0] / HDIM;
  int E = in_sizes[2];
  int M = N * RREL;
  const int* srcp = ei;
  const int* dstp = ei + E;

  char* p = (char*)d_ws;
  auto carve = [&](size_t bytes) { char* r = p; p += (bytes + 255) & ~(size_t)255; return r; };
  float*  h_a     = (float*)carve((size_t)N * HDIM * 4);
  float*  h_b     = (float*)carve((size_t)N * HDIM * 4);
  ushort* hb_a    = (ushort*)carve((size_t)N * HDIM * 2);
  ushort* hb_b    = (ushort*)carve((size_t)N * HDIM * 2);
  uint*   sorted  = (uint*)carve((size_t)E * 4);
  uint*   deg8    = (uint*)carve((size_t)M * 4);
  uint*   off8    = (uint*)carve((size_t)(M + 1) * 4);
  uint*   bsum    = (uint*)carve(4096);
  ushort* wt_lin1 = (ushort*)carve((size_t)HDIM * HDIM * 2);
  ushort* wt_conv = (ushort*)carve((size_t)2 * HDIM * KCAT * 2);

  hipMemsetAsync(deg8, 0, (size_t)M * 4, stream);

  int eb    = (E + 255) / 256;
  int nb    = (N + 255) / 256;
  int nwg   = (N + NPB - 1) / NPB;
  int nblk1 = (M + 1023) / 1024;   // <= 1024 (N <= 131072)
  int mb    = (M + 255) / 256;

  k_prep_wt<<<(2 * HDIM * KCAT + 255) / 256, 256, 0, stream>>>(lin1_w, bases, comp, root, wt_lin1, wt_conv);
  k_hist<<<eb, 256, 0, stream>>>(dstp, et, E, deg8);
  k_scan1<<<nblk1, 256, 0, stream>>>(deg8, off8, bsum, M);
  k_scan2<<<1, 1024, 0, stream>>>(bsum, off8, nblk1, M, (uint)E);
  k_scan3<<<mb, 256, 0, stream>>>(off8, bsum, M);
  k_scatter<<<eb, 256, 0, stream>>>(srcp, dstp, et, E, off8, deg8, sorted);

  k_lin1<<<nwg, 256, 0, stream>>>(x, wt_lin1, lin1_b, h_a, hb_a, N);
  k_conv<<<nwg, 256, 0, stream>>>(off8, sorted, h_a, hb_a, wt_conv, cbias, h_b, hb_b, N);
  k_conv<<<nwg, 256, 0, stream>>>(off8, sorted, h_b, hb_b, wt_conv + HDIM * KCAT, cbias + HDIM, h_a, hb_a, N);
  k_lin2<<<nb, 256, 0, stream>>>(h_a, lin2_w, lin2_b, out, N);
}

// Round 6
// 373.919 us; speedup vs baseline: 3.4493x; 1.0286x over previous
//
#include <hip/hip_runtime.h>

// ResRGCN: h=x@W1+b1; 2x {per-(dst,rel) mean aggr -> [h|agg]@[root;W_r]+bias, h+=relu}; out=h@W2+b2
// Layer 3 of the reference is dead (output discarded) and is skipped.
// Edges counting-sorted by key = dst*8+type -> per-(node,rel) segments contiguous.
// k_conv per node: chunk-of-16 walk; indices forced to SGPRs (readfirstlane) so
// each gather is SGPR-base + shared lane voffset -> 16 loads truly in flight at
// ~28 VGPRs (r5 post-mortem: VGPR=32 had serialized the chain).
// All inter-kernel feature traffic is bf16 (residual read from the LDS self row).

#define HDIM 64
#define RREL 8
#define KCAT 576   // 64 (root/self) + 8*64 (relations)
#define NPB  16    // nodes per workgroup in MFMA kernels
#define APAD 584   // padded LDS row

typedef short  short8 __attribute__((ext_vector_type(8)));
typedef __bf16 bf16x8 __attribute__((ext_vector_type(8)));
typedef float  f32x4  __attribute__((ext_vector_type(4)));
typedef unsigned int uint;
typedef unsigned short ushort;

static __device__ __forceinline__ ushort f2bf(float f) {
  uint u = __builtin_bit_cast(uint, f);
  u += 0x7FFFu + ((u >> 16) & 1u);
  return (ushort)(u >> 16);
}
static __device__ __forceinline__ float bf2f(ushort s) {
  uint u = ((uint)s) << 16;
  return __builtin_bit_cast(float, u);
}

// ---- weight prep: wt_lin1[j][k]=lin1_w[k][j]; wt_conv[l][j][k] = cat(root_l, W_r)^T in bf16
__global__ void k_prep_wt(const float* __restrict__ lin1_w, const float* __restrict__ bases,
                          const float* __restrict__ comp, const float* __restrict__ root,
                          ushort* __restrict__ wt_lin1, ushort* __restrict__ wt_conv) {
  int t = blockIdx.x * 256 + threadIdx.x;
  if (t < HDIM * HDIM) {
    int j = t >> 6, k = t & 63;
    wt_lin1[t] = f2bf(lin1_w[k * HDIM + j]);
  }
  if (t < 2 * HDIM * KCAT) {
    int l = t / (HDIM * KCAT);
    int rem = t - l * (HDIM * KCAT);
    int j = rem / KCAT;
    int k = rem - j * KCAT;
    float v;
    if (k < HDIM) {
      v = root[(l * HDIM + k) * HDIM + j];
    } else {
      int r = (k - HDIM) >> 6;
      int i = (k - HDIM) & 63;
      v = 0.f;
      #pragma unroll
      for (int b = 0; b < 4; ++b)
        v += comp[(l * RREL + r) * 4 + b] * bases[((l * 4 + b) * HDIM + i) * HDIM + j];
    }
    wt_conv[t] = f2bf(v);
  }
}

// ---- build CSR over keys = dst*8 + type (M = 8N bins)
__global__ void k_hist(const int* __restrict__ dst, const int* __restrict__ et, int E,
                       uint* __restrict__ deg) {
  int e = blockIdx.x * 256 + threadIdx.x;
  if (e < E) atomicAdd(&deg[dst[e] * RREL + et[e]], 1u);
}

__global__ void k_scan1(const uint* __restrict__ deg, uint* __restrict__ off,
                        uint* __restrict__ bsum, int M) {
  __shared__ uint s[256];
  int t = threadIdx.x;
  int base = blockIdx.x * 1024 + t * 4;
  uint v0 = 0, v1 = 0, v2 = 0, v3 = 0;
  if (base + 3 < M) {
    uint4 u = *(const uint4*)(deg + base);
    v0 = u.x; v1 = u.y; v2 = u.z; v3 = u.w;
  } else {
    if (base < M)     v0 = deg[base];
    if (base + 1 < M) v1 = deg[base + 1];
    if (base + 2 < M) v2 = deg[base + 2];
    if (base + 3 < M) v3 = deg[base + 3];
  }
  uint tsum = v0 + v1 + v2 + v3;
  s[t] = tsum;
  __syncthreads();
  for (int o = 1; o < 256; o <<= 1) {
    uint u = (t >= o) ? s[t - o] : 0u;
    __syncthreads();
    s[t] += u;
    __syncthreads();
  }
  uint ex = s[t] - tsum;
  if (base < M)     off[base]     = ex;
  if (base + 1 < M) off[base + 1] = ex + v0;
  if (base + 2 < M) off[base + 2] = ex + v0 + v1;
  if (base + 3 < M) off[base + 3] = ex + v0 + v1 + v2;
  if (t == 255) bsum[blockIdx.x] = s[255];
}

__global__ void k_scan2(uint* __restrict__ bsum, uint* __restrict__ off, int nblk, int M, uint E) {
  __shared__ uint s[1024];
  int t = threadIdx.x;
  uint v = (t < nblk) ? bsum[t] : 0u;
  s[t] = v;
  __syncthreads();
  for (int o = 1; o < 1024; o <<= 1) {
    uint u = (t >= o) ? s[t - o] : 0u;
    __syncthreads();
    s[t] += u;
    __syncthreads();
  }
  if (t < nblk) bsum[t] = s[t] - v;
  if (t == 0) off[M] = E;
}

__global__ void k_scan3(uint* __restrict__ off, const uint* __restrict__ bsum, int M) {
  int i = blockIdx.x * 256 + threadIdx.x;
  if (i < M) off[i] += bsum[i >> 10];
}

// counting-sort scatter; atomicSub on deg leaves it zeroed (self-restoring)
__global__ void k_scatter(const int* __restrict__ src, const int* __restrict__ dst,
                          const int* __restrict__ et, int E, const uint* __restrict__ off,
                          uint* __restrict__ deg, uint* __restrict__ sorted) {
  int e = blockIdx.x * 256 + threadIdx.x;
  if (e < E) {
    int key = dst[e] * RREL + et[e];
    uint p = off[key] + atomicSub(&deg[key], 1u) - 1u;
    sorted[p] = (uint)src[e];
  }
}

// ---- lin1: hb = bf16(x @ W1 + b1) (MFMA over K=64)
__global__ void k_lin1(const float* __restrict__ x, const ushort* __restrict__ wt,
                       const float* __restrict__ bias, ushort* __restrict__ hb, int N) {
  __shared__ ushort A[NPB][72];
  int nodebase = blockIdx.x * NPB;
  for (int i = threadIdx.x; i < NPB * HDIM; i += 256) {
    int nl = i >> 6, c = i & 63;
    int n = nodebase + nl;
    A[nl][c] = (n < N) ? f2bf(x[(size_t)n * HDIM + c]) : (ushort)0;
  }
  __syncthreads();
  int lane = threadIdx.x & 63, wid = threadIdx.x >> 6;
  int m16 = lane & 15, khi = lane >> 4;
  int colbase = wid * 16;
  f32x4 acc = {0.f, 0.f, 0.f, 0.f};
  #pragma unroll
  for (int kk = 0; kk < HDIM; kk += 32) {
    int k0 = kk + khi * 8;
    short8 av = *(const short8*)&A[m16][k0];
    short8 bv = *(const short8*)&wt[(colbase + m16) * HDIM + k0];
    acc = __builtin_amdgcn_mfma_f32_16x16x32_bf16(
        __builtin_bit_cast(bf16x8, av), __builtin_bit_cast(bf16x8, bv), acc, 0, 0, 0);
  }
  int j = colbase + m16;
  float bj = bias[j];
  #pragma unroll
  for (int r = 0; r < 4; ++r) {
    int nl = khi * 4 + r;
    int n = nodebase + nl;
    if (n < N) hb[(size_t)n * HDIM + j] = f2bf(acc[r] + bj);
  }
}

// ---- fused RGCN layer: chunk-16 SGPR-base gather pipeline + scalar boundary-flush walk
__global__ void __launch_bounds__(256, 6)
k_conv(const uint* __restrict__ off8, const uint* __restrict__ sorted,
       const ushort* __restrict__ hb_in, const ushort* __restrict__ wt,
       const float* __restrict__ bias, ushort* __restrict__ hb_out, int N) {
  __shared__ ushort A[NPB][APAD];
  int nodebase = blockIdx.x * NPB;
  int lane = threadIdx.x & 63, wid = threadIdx.x >> 6;
  const ushort* hlane = hb_in + lane;

  for (int q = 0; q < 4; ++q) {
    int nl = wid * 4 + q;
    int n = nodebase + nl;
    if (n < N) {
      A[nl][lane] = hb_in[(uint)n * HDIM + lane];
      // boundaries: lanes 0..8 hold off8[n*8 .. n*8+8]
      uint bv = (lane < 9) ? off8[(uint)n * RREL + lane] : 0u;
      uint s0 = (uint)__builtin_amdgcn_readlane((int)bv, 0);
      uint s1 = (uint)__builtin_amdgcn_readlane((int)bv, 8);
      float run = 0.f;
      int rel = 0;
      uint prevb = s0;
      uint nextb = (uint)__builtin_amdgcn_readlane((int)bv, 1);
      for (uint base = s0; base < s1; base += 16u) {
        // 16 index words via scalar loads (may overrun segment; reads stay in ws)
        const uint* sp = sorted + base;
        uint4 w0 = *(const uint4*)(sp);
        uint4 w1 = *(const uint4*)(sp + 4);
        uint4 w2 = *(const uint4*)(sp + 8);
        uint4 w3 = *(const uint4*)(sp + 12);
        uint idx[16] = {w0.x, w0.y, w0.z, w0.w, w1.x, w1.y, w1.z, w1.w,
                        w2.x, w2.y, w2.z, w2.w, w3.x, w3.y, w3.z, w3.w};
        float g[16];
        #pragma unroll
        for (int j = 0; j < 16; ++j) {
          // force scalar: SGPR base = hb + idx*128B, shared voffset = lane*2
          uint ij = (uint)__builtin_amdgcn_readfirstlane((int)idx[j]) & 0x1FFFFu;
          g[j] = bf2f(hlane[(size_t)ij << 6]);
        }
        uint m = s1 - base;                                       // scalar
        #pragma unroll
        for (int j = 0; j < 16; ++j) {
          if ((uint)j < m) {                                      // scalar branch
            uint pos = base + (uint)j;
            while (pos >= nextb) {                                // scalar flush walk
              float mean = run * __builtin_amdgcn_rcpf(fmaxf((float)(nextb - prevb), 1.0f));
              A[nl][HDIM + rel * HDIM + lane] = f2bf(mean);
              run = 0.f;
              ++rel;
              prevb = nextb;
              nextb = (uint)__builtin_amdgcn_readlane((int)bv, rel + 1);
            }
            run += g[j];
          }
        }
      }
      while (rel < RREL) {                                        // trailing flushes
        float mean = run * __builtin_amdgcn_rcpf(fmaxf((float)(nextb - prevb), 1.0f));
        A[nl][HDIM + rel * HDIM + lane] = f2bf(mean);
        run = 0.f;
        ++rel;
        prevb = nextb;
        if (rel < RREL)
          nextb = (uint)__builtin_amdgcn_readlane((int)bv, rel + 1);
      }
    } else {
      A[nl][lane] = 0;
      #pragma unroll
      for (int r = 0; r < RREL; ++r) A[nl][HDIM + r * HDIM + lane] = 0;
    }
  }
  __syncthreads();

  int m16 = lane & 15, khi = lane >> 4;
  int colbase = wid * 16;
  f32x4 acc = {0.f, 0.f, 0.f, 0.f};
  #pragma unroll
  for (int kk = 0; kk < KCAT; kk += 32) {
    int k0 = kk + khi * 8;
    short8 av = *(const short8*)&A[m16][k0];
    short8 bv = *(const short8*)&wt[(uint)(colbase + m16) * KCAT + k0];
    acc = __builtin_amdgcn_mfma_f32_16x16x32_bf16(
        __builtin_bit_cast(bf16x8, av), __builtin_bit_cast(bf16x8, bv), acc, 0, 0, 0);
  }
  int j = colbase + m16;
  float bj = bias[j];
  #pragma unroll
  for (int r = 0; r < 4; ++r) {
    int nl = khi * 4 + r;
    int n = nodebase + nl;
    if (n < N) {
      float hs = bf2f(A[nl][j]);                 // self row from LDS (residual base)
      float hn = hs + fmaxf(acc[r] + bj, 0.f);
      hb_out[(uint)n * HDIM + j] = f2bf(hn);
    }
  }
}

// ---- lin2: out = h @ W2 + b2  (OUT=2), bf16 input rows via short8 loads
__global__ void k_lin2(const ushort* __restrict__ hb, const float* __restrict__ w,
                       const float* __restrict__ b, float* __restrict__ out, int N) {
  int n = blockIdx.x * 256 + threadIdx.x;
  if (n >= N) return;
  const short8* hr = (const short8*)(hb + (size_t)n * HDIM);
  float a0 = b[0], a1 = b[1];
  #pragma unroll
  for (int i = 0; i < 8; ++i) {
    short8 hv8 = hr[i];
    #pragma unroll
    for (int k = 0; k < 8; ++k) {
      float hv = bf2f((ushort)hv8[k]);
      a0 += hv * w[2 * (i * 8 + k)];
      a1 += hv * w[2 * (i * 8 + k) + 1];
    }
  }
  out[2 * n] = a0;
  out[2 * n + 1] = a1;
}

extern "C" void kernel_launch(void* const* d_in, const int* in_sizes, int n_in,
                              void* d_out, int out_size, void* d_ws, size_t ws_size,
                              hipStream_t stream) {
  const float* x      = (const float*)d_in[0];
  const int*   ei     = (const int*)d_in[1];
  const int*   et     = (const int*)d_in[2];
  const float* lin1_w = (const float*)d_in[3];
  const float* lin1_b = (const float*)d_in[4];
  const float* bases  = (const float*)d_in[5];
  const float* comp   = (const float*)d_in[6];
  const float* root   = (const float*)d_in[7];
  const float* cbias  = (const float*)d_in[8];
  const float* lin2_w = (const float*)d_in[9];
  const float* lin2_b = (const float*)d_in[10];
  float* out = (float*)d_out;

  int N = in_sizes[0] / HDIM;
  int E = in_sizes[2];
  int M = N * RREL;
  const int* srcp = ei;
  const int* dstp = ei + E;

  char* p = (char*)d_ws;
  auto carve = [&](size_t bytes) { char* r = p; p += (bytes + 255) & ~(size_t)255; return r; };
  ushort* hb_a    = (ushort*)carve((size_t)N * HDIM * 2);
  ushort* hb_b    = (ushort*)carve((size_t)N * HDIM * 2);
  uint*   sorted  = (uint*)carve((size_t)E * 4);
  uint*   deg8    = (uint*)carve((size_t)M * 4);
  uint*   off8    = (uint*)carve((size_t)(M + 1) * 4);
  uint*   bsum    = (uint*)carve(4096);
  ushort* wt_lin1 = (ushort*)carve((size_t)HDIM * HDIM * 2);
  ushort* wt_conv = (ushort*)carve((size_t)2 * HDIM * KCAT * 2);
  carve((size_t)8 << 20);  // slack so masked (<2^17) gather overruns stay in ws

  hipMemsetAsync(deg8, 0, (size_t)M * 4, stream);

  int eb    = (E + 255) / 256;
  int nb    = (N + 255) / 256;
  int nwg   = (N + NPB - 1) / NPB;
  int nblk1 = (M + 1023) / 1024;   // <= 1024 (N <= 131072)
  int mb    = (M + 255) / 256;

  k_prep_wt<<<(2 * HDIM * KCAT + 255) / 256, 256, 0, stream>>>(lin1_w, bases, comp, root, wt_lin1, wt_conv);
  k_hist<<<eb, 256, 0, stream>>>(dstp, et, E, deg8);
  k_scan1<<<nblk1, 256, 0, stream>>>(deg8, off8, bsum, M);
  k_scan2<<<1, 1024, 0, stream>>>(bsum, off8, nblk1, M, (uint)E);
  k_scan3<<<mb, 256, 0, stream>>>(off8, bsum, M);
  k_scatter<<<eb, 256, 0, stream>>>(srcp, dstp, et, E, off8, deg8, sorted);

  k_lin1<<<nwg, 256, 0, stream>>>(x, wt_lin1, lin1_b, hb_a, N);
  k_conv<<<nwg, 256, 0, stream>>>(off8, sorted, hb_a, wt_conv, cbias, hb_b, N);
  k_conv<<<nwg, 256, 0, stream>>>(off8, sorted, hb_b, wt_conv + HDIM * KCAT, cbias + HDIM, hb_a, N);
  k_lin2<<<nb, 256, 0, stream>>>(hb_a, lin2_w, lin2_b, out, N);
}